// Round 2
// baseline (16198.874 us; speedup 1.0000x reference)
//
#include <hip/hip_runtime.h>
#include <hip/hip_cooperative_groups.h>

namespace cg = cooperative_groups;

// Problem constants (match reference)
#define TSTEPS 500
#define NB     64      // batch
#define NINP   64
#define NHID   1024
#define NOUTV  3
#define ALPHA_F 0.1f

// Recurrent kernel geometry
#define NWG    256     // one block per CU
#define NTHR   256     // 4 waves
#define CJ     32      // j-rows of rT per staged chunk (32*64*4B = 8KB)
#define NCH    8       // chunks per wave's j-quarter (256 j)

// r ping-pong buffer in static device memory: [2][NHID][NB] (r transposed so
// lane=b accesses are coalesced / conflict-free). 512 KB — avoids any
// dependence on ws_size.
__device__ float g_rT[2 * NHID * NB];

// ---------------------------------------------------------------------------
// Persistent cooperative kernel: the serial T-loop.
//   wg g owns h in [g*4, g*4+4); wave w of the wg accumulates the j-quarter
//   [w*256, w*256+256) for all 4 h's (lane = batch). Cross-wave K-reduction
//   via LDS, then wave w finalizes h = g*4 + w.
// ---------------------------------------------------------------------------
__global__ __launch_bounds__(NTHR)
void rnn_loop_kernel(const float* __restrict__ X,
                     const float* __restrict__ hidden1,
                     const float* __restrict__ Wih,
                     const float* __restrict__ Whh,
                     float* __restrict__ hid_out)   // [T][B][NHID]
{
    __shared__ float sbuf[4][2][CJ * NB];   // 4 waves x dbuf x 8KB = 64KB exactly

    const int tid  = threadIdx.x;
    const int lane = tid & 63;
    const int w    = __builtin_amdgcn_readfirstlane(tid >> 6); // wave id, force SGPR
    const int g    = blockIdx.x;
    const int hq   = g * 4;            // h-group base
    const int hmine = hq + w;          // h this wave finalizes

    const float* wr0 = Whh + (size_t)(hq + 0) * NHID;
    const float* wr1 = Whh + (size_t)(hq + 1) * NHID;
    const float* wr2 = Whh + (size_t)(hq + 2) * NHID;
    const float* wr3 = Whh + (size_t)(hq + 3) * NHID;
    const float* wih = Wih + (size_t)hmine * NINP;

    // transpose buffer for coalesced hid_out stores: r for [h=hq+w][b]
    float* red2 = &sbuf[0][1][0];      // [4][64] floats, reused area

    // persistent state x[b=lane][hmine] in a register for the whole loop
    float x = hidden1[(size_t)lane * NHID + hmine];
    float r = tanhf(x);
    g_rT[(size_t)hmine * NB + lane] = r;
    cg::this_grid().sync();

    int p = 0;
    const int jq = w * 256;            // this wave's j-quarter base

    for (int t = 0; t < TSTEPS; ++t) {
        const float* rsrc = g_rT + (size_t)p * NHID * NB;

        // stage chunk 0 of this wave's quarter (wave-private, async to LDS)
        {
            const char* gsrc = (const char*)(rsrc + (size_t)jq * NB);
            char* lbase = (char*)&sbuf[w][0][0];
            #pragma unroll
            for (int q = 0; q < 8; ++q) {
                __builtin_amdgcn_global_load_lds(
                    (const __attribute__((address_space(1))) void*)(gsrc + q * 1024 + lane * 16),
                    (__attribute__((address_space(3))) void*)(lbase + q * 1024),
                    16, 0, 0);
            }
        }

        float a0 = 0.f, a1 = 0.f, a2 = 0.f, a3 = 0.f;

        #pragma unroll 1   // keep staging/waitcnt structure intact
        for (int k = 0; k < NCH; ++k) {
            if (k + 1 < NCH) {
                // prefetch next chunk into the other buffer
                const char* gsrc = (const char*)(rsrc + (size_t)(jq + (k + 1) * CJ) * NB);
                char* lbase = (char*)&sbuf[w][(k + 1) & 1][0];
                #pragma unroll
                for (int q = 0; q < 8; ++q) {
                    __builtin_amdgcn_global_load_lds(
                        (const __attribute__((address_space(1))) void*)(gsrc + q * 1024 + lane * 16),
                        (__attribute__((address_space(3))) void*)(lbase + q * 1024),
                        16, 0, 0);
                }
                // wait for current chunk (leave the 8 just-issued in flight)
                asm volatile("s_waitcnt vmcnt(8)" ::: "memory");
            } else {
                asm volatile("s_waitcnt vmcnt(0)" ::: "memory");
            }

            const float* buf = &sbuf[w][k & 1][0];
            const int jb = jq + k * CJ;
            #pragma unroll 8
            for (int j = 0; j < CJ; ++j) {
                float rv = buf[j * NB + lane];        // ds_read_b32, 2-way (free)
                a0 = fmaf(wr0[jb + j], rv, a0);       // Whh via scalar loads (uniform)
                a1 = fmaf(wr1[jb + j], rv, a1);
                a2 = fmaf(wr2[jb + j], rv, a2);
                a3 = fmaf(wr3[jb + j], rv, a3);
            }
        }

        // cross-wave K-reduction via LDS (all stage loads drained: vmcnt(0))
        {
            float* red = &sbuf[w][0][0];
            red[0 * NB + lane] = a0;
            red[1 * NB + lane] = a1;
            red[2 * NB + lane] = a2;
            red[3 * NB + lane] = a3;
        }
        __syncthreads();
        float dot = sbuf[0][0][w * NB + lane] + sbuf[1][0][w * NB + lane]
                  + sbuf[2][0][w * NB + lane] + sbuf[3][0][w * NB + lane];

        // input projection for hmine: sum_i Wih[hmine][i] * X[t][b][i]
        float xw = 0.f;
        const float4* xp = (const float4*)(X + ((size_t)t * NB + lane) * NINP);
        #pragma unroll
        for (int i = 0; i < NINP / 4; ++i) {
            float4 v = xp[i];
            xw = fmaf(wih[4 * i + 0], v.x, xw);
            xw = fmaf(wih[4 * i + 1], v.y, xw);
            xw = fmaf(wih[4 * i + 2], v.z, xw);
            xw = fmaf(wih[4 * i + 3], v.w, xw);
        }

        // leaky-integrator update + tanh (matches reference: x += a*(-x + mm))
        x = fmaf(ALPHA_F, dot + xw - x, x);
        r = tanhf(x);

        // r for next step (coalesced: 64 lanes x 4B contiguous)
        g_rT[(size_t)(p ^ 1) * NHID * NB + (size_t)hmine * NB + lane] = r;

        // transpose r through LDS so hid_out gets ONE dwordx4 store per block
        red2[w * NB + lane] = r;
        __syncthreads();
        if (w == 0) {
            float4 v;
            v.x = red2[0 * NB + lane];
            v.y = red2[1 * NB + lane];
            v.z = red2[2 * NB + lane];
            v.w = red2[3 * NB + lane];
            // hid_out[t][b=lane][hq..hq+3], 16B-aligned (hq % 4 == 0)
            *(float4*)(hid_out + ((size_t)t * NB + lane) * NHID + hq) = v;
        }

        cg::this_grid().sync();
        p ^= 1;
    }
}

// ---------------------------------------------------------------------------
// Parallel readout: one wave per (t,b). outv = r@Woutᵀ + bout; outp = pj@outv.
// ---------------------------------------------------------------------------
__global__ __launch_bounds__(256)
void out_proj_kernel(const float* __restrict__ hid,      // [T*B][NHID]
                     const float* __restrict__ perturb,  // [T*B][3][3]
                     const float* __restrict__ Wout,     // [3][NHID]
                     const float* __restrict__ bout,     // [3]
                     float* __restrict__ outv,           // [T*B][3]
                     float* __restrict__ outp)           // [T*B][3]
{
    const int gw   = (int)((blockIdx.x * blockDim.x + threadIdx.x) >> 6);
    const int lane = threadIdx.x & 63;
    if (gw >= TSTEPS * NB) return;

    const float4* r4  = (const float4*)(hid + (size_t)gw * NHID);
    const float4* w04 = (const float4*)(Wout);
    const float4* w14 = (const float4*)(Wout + NHID);
    const float4* w24 = (const float4*)(Wout + 2 * NHID);

    float s0 = 0.f, s1 = 0.f, s2 = 0.f;
    #pragma unroll
    for (int q = 0; q < 4; ++q) {
        int idx = lane * 4 + q;                 // h = idx*4 .. idx*4+3
        float4 v = r4[idx];
        float4 a = w04[idx]; s0 += v.x * a.x + v.y * a.y + v.z * a.z + v.w * a.w;
        float4 b = w14[idx]; s1 += v.x * b.x + v.y * b.y + v.z * b.z + v.w * b.w;
        float4 c = w24[idx]; s2 += v.x * c.x + v.y * c.y + v.z * c.z + v.w * c.w;
    }
    #pragma unroll
    for (int m = 1; m < 64; m <<= 1) {
        s0 += __shfl_xor(s0, m, 64);
        s1 += __shfl_xor(s1, m, 64);
        s2 += __shfl_xor(s2, m, 64);
    }
    if (lane == 0) {
        float o0 = s0 + bout[0];
        float o1 = s1 + bout[1];
        float o2 = s2 + bout[2];
        float* ov = outv + (size_t)gw * 3;
        ov[0] = o0; ov[1] = o1; ov[2] = o2;
        const float* pj = perturb + (size_t)gw * 9;
        float* op = outp + (size_t)gw * 3;
        op[0] = pj[0] * o0 + pj[1] * o1 + pj[2] * o2;
        op[1] = pj[3] * o0 + pj[4] * o1 + pj[5] * o2;
        op[2] = pj[6] * o0 + pj[7] * o1 + pj[8] * o2;
    }
}

// ---------------------------------------------------------------------------
extern "C" void kernel_launch(void* const* d_in, const int* in_sizes, int n_in,
                              void* d_out, int out_size, void* d_ws, size_t ws_size,
                              hipStream_t stream)
{
    const float* X       = (const float*)d_in[0];
    const float* perturb = (const float*)d_in[1];
    const float* hidden1 = (const float*)d_in[2];
    const float* Wih     = (const float*)d_in[3];
    const float* Whh     = (const float*)d_in[4];
    const float* Wout    = (const float*)d_in[5];
    const float* bout    = (const float*)d_in[6];

    float* out  = (float*)d_out;
    float* outv = out;
    float* outp = out + (size_t)TSTEPS * NB * NOUTV;                 // +96000
    float* hid  = out + (size_t)2 * TSTEPS * NB * NOUTV;             // +192000

    void* args[] = { (void*)&X, (void*)&hidden1, (void*)&Wih, (void*)&Whh,
                     (void*)&hid };
    hipLaunchCooperativeKernel((void*)rnn_loop_kernel, dim3(NWG), dim3(NTHR),
                               args, 0, stream);

    // readout: 32000 (t,b) waves, 4 waves/block
    out_proj_kernel<<<dim3((TSTEPS * NB) / 4), dim3(256), 0, stream>>>(
        hid, perturb, Wout, bout, outv, outp);
}